// Round 1
// baseline (774.671 us; speedup 1.0000x reference)
//
#include <hip/hip_runtime.h>
#include <hip/hip_bf16.h>

// QRNN: T=512, B=64, IN=512, H=1024, OUT=512. fp32 in/out.
// R7: fast activations in gemm<0> epilogue. tanhf/expf (libm __ocml, ~25-35
// instrs w/ divide) replaced by v_exp_f32 + v_rcp_f32 via builtins:
//   sigmoid(x) = rcp(1 + exp2(-log2e*x)); tanh(x) = 1 - 2*rcp(1+exp2(2log2e*x))
// merged branch-free as v = a*rcp(1+exp2(k*v)) + d with wave-uniform (a,k,d).
// Theory: MODE-0 epilogue (64 transcendentals/thread) was ~3-5x the K=512
// main-loop MFMA cycles -> epilogue-bound. Accuracy ~1e-6 rel << bf16 quant.
// R6 retained: bf16 g, x_bf aliased into h1, CW=256 chunks, register scan_p2.
// ws layout (CW=256 => 192 MiB total):
//   h0  : bf16 QM*QH          (64 MiB)
//   h1  : bf16 QM*QH          (64 MiB; x_bf bf16 QM*QIN aliased in first 32)
//   W0T : bf16 3QH*QIN        (3 MiB)
//   W1T : bf16 3QH*QH         (6 MiB)
//   WfcT: bf16 QOUT*QH        (1 MiB)
//   Aseg/Bseg/cstart: fp32 QB*CW*SEG each
//   g   : bf16 QM*3*CW

#define QT 512
#define QB 64
#define QIN 512
#define QH 1024
#define QOUT 512
#define QM (QT * QB)
#define SEG 32
#define SL (QT / SEG)  // 16

typedef unsigned short ushort_t;
typedef __attribute__((ext_vector_type(8))) short bf16x8;
typedef __attribute__((ext_vector_type(4))) float f32x4;

__device__ __forceinline__ float u2f(ushort_t u) {
    union { unsigned int i; float f; } v;
    v.i = ((unsigned int)u) << 16;
    return v.f;
}

__device__ __forceinline__ ushort_t f2bf(float f) {
    union { float f; unsigned int i; } v;
    v.f = f;
    unsigned int r = v.i + 0x7fffu + ((v.i >> 16) & 1u);  // RNE
    return (ushort_t)(r >> 16);
}

__device__ __forceinline__ void glds16(const ushort_t* g, ushort_t* l) {
    __builtin_amdgcn_global_load_lds(
        (const __attribute__((address_space(1))) void*)g,
        (__attribute__((address_space(3))) void*)l, 16, 0, 0);
}

// --------------------------- pre-pass kernels ------------------------------
__global__ __launch_bounds__(256) void cvt_bf16(const float* __restrict__ src,
                                                ushort_t* __restrict__ dst) {
    const int i = blockIdx.x * 256 + threadIdx.x;
    float4 v = ((const float4*)src)[i];
    ushort4 o;
    o.x = f2bf(v.x); o.y = f2bf(v.y); o.z = f2bf(v.z); o.w = f2bf(v.w);
    ((ushort4*)dst)[i] = o;
}

// W (K x N fp32) -> WT (N x K bf16)
__global__ __launch_bounds__(256) void transpose_cvt(
    const float* __restrict__ W, ushort_t* __restrict__ WT, int K, int N) {
    __shared__ float t[32][33];
    const int tx = threadIdx.x & 31, ty = threadIdx.x >> 5;
    const int n0 = blockIdx.x * 32, k0 = blockIdx.y * 32;
#pragma unroll
    for (int i = 0; i < 4; ++i)
        t[ty + 8 * i][tx] = W[(size_t)(k0 + ty + 8 * i) * N + n0 + tx];
    __syncthreads();
#pragma unroll
    for (int i = 0; i < 4; ++i)
        WT[(size_t)(n0 + ty + 8 * i) * K + k0 + tx] = f2bf(t[tx][ty + 8 * i]);
}

// ------------------------------ MFMA GEMM ----------------------------------
// C = A(M x K, bf16 row-major) @ BT(N x K, bf16 row-major)^T.
// MODE 0: out bf16 g-chunk (M x 3*CW), tanh (gate 0) / sigmoid (gates 1,2).
// MODE 1: FC, fp32 out, bias only. 256 thr = 4 waves, tile 128x128, BK=64.
template <int MODE>
__global__ __launch_bounds__(256) void gemm_mfma(
    const ushort_t* __restrict__ A, const ushort_t* __restrict__ BT,
    const float* __restrict__ bias, void* __restrict__ out,
    int K, int c0, int CW) {
    __shared__ ushort_t As[128 * 64];
    __shared__ ushort_t Bs[128 * 64];

    const int tid = threadIdx.x;
    const int lane = tid & 63;
    const int w = tid >> 6;
    const int wr = w >> 1, wc = w & 1;
    const int m0 = blockIdx.y * 128;

    int nW, nOut, outstride, gate = 0;
    if (MODE == 0) {
        const int per = CW >> 7;
        gate = blockIdx.x / per;
        const int nloc = (blockIdx.x - gate * per) * 128;
        nW = gate * QH + c0 + nloc;
        nOut = gate * CW + nloc;
        outstride = 3 * CW;
    } else {
        nW = blockIdx.x * 128;
        nOut = nW;
        outstride = QOUT;
    }

    size_t aoff[4], boff[4];
    int soff[4];
#pragma unroll
    for (int j = 0; j < 4; ++j) {
        const int s = ((w * 4 + j) << 6) + lane;
        const int ms = s >> 3;
        const int kg = (s & 7) ^ (ms & 7);
        aoff[j] = (size_t)(m0 + ms) * K + kg * 8;
        boff[j] = (size_t)(nW + ms) * K + kg * 8;
        soff[j] = (w * 4 + j) << 9;
    }

    const int fl = lane & 15, fq = lane >> 4, l7 = lane & 7;
    int aidx[2][4], bidx[2][4];
#pragma unroll
    for (int ks = 0; ks < 2; ++ks)
#pragma unroll
        for (int i = 0; i < 4; ++i) {
            const int am = wr * 64 + i * 16 + fl;
            const int bn = wc * 64 + i * 16 + fl;
            const int kq = ks * 4 + fq;
            aidx[ks][i] = (am * 8 + (kq ^ l7)) * 8;
            bidx[ks][i] = (bn * 8 + (kq ^ l7)) * 8;
        }

    f32x4 acc[4][4];
#pragma unroll
    for (int i = 0; i < 4; ++i)
#pragma unroll
        for (int j = 0; j < 4; ++j) acc[i][j] = {0.f, 0.f, 0.f, 0.f};

    for (int k0 = 0; k0 < K; k0 += 64) {
        __syncthreads();
#pragma unroll
        for (int j = 0; j < 4; ++j) glds16(A + aoff[j] + k0, &As[soff[j]]);
#pragma unroll
        for (int j = 0; j < 4; ++j) glds16(BT + boff[j] + k0, &Bs[soff[j]]);
        __syncthreads();
#pragma unroll
        for (int ks = 0; ks < 2; ++ks) {
            bf16x8 af[4], bv[4];
#pragma unroll
            for (int i = 0; i < 4; ++i)
                af[i] = *(const bf16x8*)&As[aidx[ks][i]];
#pragma unroll
            for (int j = 0; j < 4; ++j)
                bv[j] = *(const bf16x8*)&Bs[bidx[ks][j]];
#pragma unroll
            for (int i = 0; i < 4; ++i)
#pragma unroll
                for (int j = 0; j < 4; ++j)
                    acc[i][j] = __builtin_amdgcn_mfma_f32_16x16x32_bf16(
                        af[i], bv[j], acc[i][j], 0, 0, 0);
        }
    }

    // Fast activation constants (wave-uniform): v = a*rcp(1+exp2(k*v)) + d.
    // gate 0 (tanh):    a=-2, k= 2*log2e, d=1
    // gate 1,2 (sigm):  a= 1, k=  -log2e, d=0
    const float ak = (gate == 0) ? 2.8853900817779268f : -1.4426950408889634f;
    const float aa = (gate == 0) ? -2.f : 1.f;
    const float ad = (gate == 0) ? 1.f : 0.f;

    // Epilogue. C/D: col = lane&15, row = (lane>>4)*4 + reg.
    const int rbase = fq * 4;
#pragma unroll
    for (int i = 0; i < 4; ++i) {
#pragma unroll
        for (int j = 0; j < 4; ++j) {
            const int col = nOut + wc * 64 + j * 16 + fl;
            const float bvv = bias[nW + wc * 64 + j * 16 + fl];
            const int row0 = m0 + wr * 64 + i * 16 + rbase;
#pragma unroll
            for (int r = 0; r < 4; ++r) {
                float v = acc[i][j][r] + bvv;
                if (MODE == 0) {
                    v = aa * __builtin_amdgcn_rcpf(
                                 1.f + __builtin_amdgcn_exp2f(ak * v)) +
                        ad;
                    ((ushort_t*)out)[(size_t)(row0 + r) * outstride + col] =
                        f2bf(v);
                } else {
                    ((float*)out)[(size_t)(row0 + r) * outstride + col] = v;
                }
            }
        }
    }
}

// ----------------------- segmented fo-scan (3 passes) ----------------------
// g: (T, B, 3, CW) bf16 activated z,f,o. c = f*c + (1-f)*z as (A,B) pairs.

// Pass 1: per-(seg,b,hh) summary. idx = (s*QB + b)*CW + hh.
__global__ __launch_bounds__(256) void scan_p1(const ushort_t* __restrict__ g,
                                               float* __restrict__ Aseg,
                                               float* __restrict__ Bseg,
                                               int CW) {
    const int idx = blockIdx.x * 256 + threadIdx.x;
    const int hh = idx % CW;
    const int sb = idx / CW;
    const int b = sb % QB;
    const int s = sb / QB;
    const ushort_t* gp = g + ((size_t)(s * SL * QB + b) * 3) * CW + hh;
    const size_t grow = (size_t)QB * 3 * CW;
    float zv[SL], fv[SL];
#pragma unroll
    for (int t = 0; t < SL; ++t) {
        zv[t] = u2f(gp[0]);
        fv[t] = u2f(gp[CW]);
        gp += grow;
    }
    float A = 1.f, Bc = 0.f;
#pragma unroll
    for (int t = 0; t < SL; ++t) {
        Bc = fv[t] * Bc + (1.f - fv[t]) * zv[t];
        A *= fv[t];
    }
    Aseg[idx] = A;
    Bseg[idx] = Bc;
}

// Pass 2: scan SEG summaries; prefetch all pairs then register chain.
__global__ __launch_bounds__(256) void scan_p2(const float* __restrict__ Aseg,
                                               const float* __restrict__ Bseg,
                                               float* __restrict__ cstart,
                                               int CW) {
    const int idx = blockIdx.x * 256 + threadIdx.x;
    const size_t stride = (size_t)QB * CW;
    float Av[SEG], Bv[SEG];
#pragma unroll
    for (int s = 0; s < SEG; ++s) {
        Av[s] = Aseg[s * stride + idx];
        Bv[s] = Bseg[s * stride + idx];
    }
    float c = 0.f;
#pragma unroll
    for (int s = 0; s < SEG; ++s) {
        cstart[s * stride + idx] = c;
        c = Av[s] * c + Bv[s];
    }
}

// Pass 3: recompute interior states, write h (bf16).
__global__ __launch_bounds__(256) void scan_p3(const ushort_t* __restrict__ g,
                                               const float* __restrict__ cstart,
                                               ushort_t* __restrict__ h,
                                               int c0, int CW) {
    const int idx = blockIdx.x * 256 + threadIdx.x;
    const int hh = idx % CW;
    const int sb = idx / CW;
    const int b = sb % QB;
    const int s = sb / QB;
    const ushort_t* gp = g + ((size_t)(s * SL * QB + b) * 3) * CW + hh;
    ushort_t* hp = h + (size_t)(s * SL * QB + b) * QH + c0 + hh;
    const size_t grow = (size_t)QB * 3 * CW;
    const size_t hrow = (size_t)QB * QH;
    float zv[SL], fv[SL], ov[SL];
#pragma unroll
    for (int t = 0; t < SL; ++t) {
        zv[t] = u2f(gp[0]);
        fv[t] = u2f(gp[CW]);
        ov[t] = u2f(gp[2 * CW]);
        gp += grow;
    }
    float c = cstart[idx];
#pragma unroll
    for (int t = 0; t < SL; ++t) {
        c = fv[t] * c + (1.f - fv[t]) * zv[t];
        *hp = f2bf(ov[t] * c);
        hp += hrow;
    }
}

extern "C" void kernel_launch(void* const* d_in, const int* in_sizes, int n_in,
                              void* d_out, int out_size, void* d_ws,
                              size_t ws_size, hipStream_t stream) {
    const float* x   = (const float*)d_in[0];
    const float* W0  = (const float*)d_in[1];
    const float* b0  = (const float*)d_in[2];
    const float* W1  = (const float*)d_in[3];
    const float* b1  = (const float*)d_in[4];
    const float* Wfc = (const float*)d_in[5];
    const float* bfc = (const float*)d_in[6];
    float* out = (float*)d_out;

    char* p = (char*)d_ws;
    ushort_t* h0   = (ushort_t*)p;  p += (size_t)QM * QH * 2;
    ushort_t* h1   = (ushort_t*)p;  // x_bf aliases h1 (dead before h1 write)
    ushort_t* x_bf = (ushort_t*)p;  p += (size_t)QM * QH * 2;
    ushort_t* W0T  = (ushort_t*)p;  p += (size_t)3 * QH * QIN * 2;
    ushort_t* W1T  = (ushort_t*)p;  p += (size_t)3 * QH * QH * 2;
    ushort_t* WfcT = (ushort_t*)p;  p += (size_t)QOUT * QH * 2;
    const size_t base = (size_t)(p - (char*)d_ws);

    // Largest CW (>=128) fitting: base + 3 summary arrays + bf16 g-chunk.
    int CW = QH;
    while (CW > 128 &&
           base + 3 * (size_t)QB * CW * SEG * 4 + (size_t)QM * 3 * CW * 2 >
               ws_size)
        CW >>= 1;
    const int nch = QH / CW;

    float* Aseg   = (float*)p;  p += (size_t)QB * CW * SEG * 4;
    float* Bseg   = (float*)p;  p += (size_t)QB * CW * SEG * 4;
    float* cstart = (float*)p;  p += (size_t)QB * CW * SEG * 4;
    ushort_t* g   = (ushort_t*)p;

    dim3 blk(256);

    cvt_bf16<<<dim3(QM * QIN / 1024), blk, 0, stream>>>(x, x_bf);
    transpose_cvt<<<dim3(3 * QH / 32, QIN / 32), blk, 0, stream>>>(
        W0, W0T, QIN, 3 * QH);
    transpose_cvt<<<dim3(3 * QH / 32, QH / 32), blk, 0, stream>>>(
        W1, W1T, QH, 3 * QH);
    transpose_cvt<<<dim3(QOUT / 32, QH / 32), blk, 0, stream>>>(
        Wfc, WfcT, QH, QOUT);

    const dim3 ggrid(3 * (CW >> 7), QM / 128);
    const dim3 p13grid(SEG * QB * CW / 256);
    const dim3 p2grid(QB * CW / 256);

    for (int ci = 0; ci < nch; ++ci) {
        gemm_mfma<0><<<ggrid, blk, 0, stream>>>(x_bf, W0T, b0, g, QIN,
                                                ci * CW, CW);
        scan_p1<<<p13grid, blk, 0, stream>>>(g, Aseg, Bseg, CW);
        scan_p2<<<p2grid, blk, 0, stream>>>(Aseg, Bseg, cstart, CW);
        scan_p3<<<p13grid, blk, 0, stream>>>(g, cstart, h0, ci * CW, CW);
    }
    for (int ci = 0; ci < nch; ++ci) {
        gemm_mfma<0><<<ggrid, blk, 0, stream>>>(h0, W1T, b1, g, QH,
                                                ci * CW, CW);
        scan_p1<<<p13grid, blk, 0, stream>>>(g, Aseg, Bseg, CW);
        scan_p2<<<p2grid, blk, 0, stream>>>(Aseg, Bseg, cstart, CW);
        scan_p3<<<p13grid, blk, 0, stream>>>(g, cstart, h1, ci * CW, CW);
    }
    gemm_mfma<1><<<dim3(QOUT / 128, QM / 128), blk, 0, stream>>>(
        h1, WfcT, bfc, out, QH, 0, 0);
}